// Round 2
// baseline (1677.906 us; speedup 1.0000x reference)
//
#include <hip/hip_runtime.h>
#include <math.h>

#define NNODES 20000
#define NEDGES 320000
#define NGRAPHS 200
#define K1 36
#define K2 26
#define NBINS 20480   // 1024 threads x 20 bins in the scan kernel (>= NNODES)

struct WPtrs { const float* w[6]; };

__device__ __forceinline__ float sigf(float v) { return 1.0f / (1.0f + expf(-v)); }
__device__ __forceinline__ float eluf(float v) { return v > 0.0f ? v : expm1f(v); }

// fast (v_exp_f32 / v_rcp_f32) variants for the edge hot loop
__device__ __forceinline__ float fsig(float v) { return __builtin_amdgcn_rcpf(1.0f + __expf(-v)); }
__device__ __forceinline__ float felu(float v) { return v > 0.0f ? v : __expf(v) - 1.0f; }

// ---------------------------------------------------------------------------
// Generic fused GEMM: out[:, chunk*128+half*64 : +64] = act(A[M,128] @ Wc[128,64])
// grid.x = ceil(M/64), grid.y = nchunks*2. 64x64 output tile per workgroup.
// ---------------------------------------------------------------------------
__global__ __launch_bounds__(256) void gemm128_kernel(
    const float* __restrict__ A, WPtrs wp, float* __restrict__ out,
    int out_stride, int act)
{
    __shared__ float4 Wl[2048];   // [k][f4]: k*16 + fq   (128 x 64 floats)
    __shared__ float4 Al[2048];   // [n][k4]: n*32 + k4   (64 x 128 floats)

    const int half  = blockIdx.y & 1;
    const int chunk = blockIdx.y >> 1;
    const float4* W4 = (const float4*)(wp.w[chunk] + half * 64);

    for (int idx = threadIdx.x; idx < 2048; idx += 256) {
        int k = idx >> 4, fq = idx & 15;
        Wl[idx] = W4[k * 32 + fq];           // row stride of W is 128 floats = 32 f4
    }
    const int m0 = blockIdx.x * 64;
    const float4* A4 = (const float4*)A;
    for (int idx = threadIdx.x; idx < 2048; idx += 256) {
        int r = idx >> 5, k4 = idx & 31;
        int row = m0 + r;
        Al[idx] = (row < NNODES) ? A4[(size_t)row * 32 + k4] : make_float4(0.f, 0.f, 0.f, 0.f);
    }
    __syncthreads();

    const int fg = threadIdx.x & 15;   // feature group: f' = fg*4
    const int ng = threadIdx.x >> 4;   // node group: n = ng*4 + j

    float acc[4][4] = {};
    #pragma unroll 4
    for (int k4 = 0; k4 < 32; ++k4) {
        float4 a[4], w[4];
        #pragma unroll
        for (int j = 0; j < 4; ++j) a[j] = Al[(ng * 4 + j) * 32 + k4];
        #pragma unroll
        for (int q = 0; q < 4; ++q) w[q] = Wl[(k4 * 4 + q) * 16 + fg];
        #pragma unroll
        for (int j = 0; j < 4; ++j) {
            const float* ap = (const float*)&a[j];
            #pragma unroll
            for (int q = 0; q < 4; ++q) {
                const float* wq = (const float*)&w[q];
                #pragma unroll
                for (int jj = 0; jj < 4; ++jj)
                    acc[j][jj] = fmaf(ap[q], wq[jj], acc[j][jj]);
            }
        }
    }

    const int coff = chunk * 128 + half * 64 + fg * 4;
    #pragma unroll
    for (int j = 0; j < 4; ++j) {
        int row = m0 + ng * 4 + j;
        if (row < NNODES) {
            float4 v; float* vp = (float*)&v;
            #pragma unroll
            for (int jj = 0; jj < 4; ++jj) {
                float t = acc[j][jj];
                vp[jj] = act ? sigf(t) : t;
            }
            *(float4*)(out + (size_t)row * out_stride + coff) = v;
        }
    }
}

// ---------------------------------------------------------------------------
// Edge-permutation build: counting sort of edge indices by source node.
// Sources are invariant across the 3 GNN blocks -> build once, use 3x.
// ---------------------------------------------------------------------------
__global__ void hist_kernel(const int* __restrict__ esrc, int* __restrict__ cnt)
{
    int i = blockIdx.x * 256 + threadIdx.x;
    if (i < NEDGES) atomicAdd(&cnt[esrc[i]], 1);
}

__global__ __launch_bounds__(1024) void scan_kernel(
    const int* __restrict__ cnt, int* __restrict__ cursor)
{
    __shared__ int ps[1024];
    const int t = threadIdx.x;
    const int b0 = t * 20;
    int sum = 0;
    #pragma unroll
    for (int b = 0; b < 20; ++b) sum += cnt[b0 + b];
    ps[t] = sum;
    __syncthreads();
    // inclusive scan over 1024 partials
    for (int off = 1; off < 1024; off <<= 1) {
        int v = (t >= off) ? ps[t - off] : 0;
        __syncthreads();
        ps[t] += v;
        __syncthreads();
    }
    int acc = ps[t] - sum;          // exclusive prefix of this thread's chunk
    #pragma unroll
    for (int b = 0; b < 20; ++b) {
        int c = cnt[b0 + b];
        cursor[b0 + b] = acc;
        acc += c;
    }
}

__global__ void scatter_kernel(const int* __restrict__ esrc,
                               int* __restrict__ cursor, int* __restrict__ eperm)
{
    int i = blockIdx.x * 256 + threadIdx.x;
    if (i < NEDGES) {
        int p = atomicAdd(&cursor[esrc[i]], 1);
        eperm[p] = i;
    }
}

// ---------------------------------------------------------------------------
// Edge kernel: z = sigmoid(g)*elu(m)*(cs@W1v + (pw@W2v)*sigmoid(pw@W2vg))
// g/m reconstructed from gathered node-level products P[n][6][128].
//
// R3 post-mortem: k-outer 4-edge unroll removed the VALU fat (VALUBusy 75->44)
//   but dur/hbm_gbps were flat -> the memory system is at its ceiling for the
//   RANDOM gather pattern (~3 TB/s), not concurrency-limited.
// R4: (a) process edges in source-sorted order (eperm) -> source-side P rows
//   and the x[] atomics become node-local; 4-edge groups usually share one
//   source -> in-register merge before atomicAdd.
//   (b) weights now in LDS (45 KB, addr k*128+f -> 2 lanes/bank = free),
//   512-thread blocks -> no AGPR residue, LDS caps occupancy at 3 blocks
//   x 8 waves = 24 waves/CU (was 13).
// 512 threads = 4 edge-slots x 128 features, 4-edge unroll, 64 edges/block.
// ---------------------------------------------------------------------------
__global__ __launch_bounds__(512, 4) void edge_kernel(
    const float* __restrict__ P, const int* __restrict__ eperm,
    const int* __restrict__ esrc, const int* __restrict__ etgt,
    const float* __restrict__ dist,
    const float* __restrict__ cs, const float* __restrict__ pw,
    const float* __restrict__ W1v, const float* __restrict__ W2v,
    const float* __restrict__ W2vg,
    float* __restrict__ x)
{
    __shared__ float wl[(K1 + 2 * K2) * 128];   // 88 x 128 floats = 45 KB

    const int f = threadIdx.x & 127;
    for (int idx = threadIdx.x; idx < K1 * 128; idx += 512) wl[idx] = W1v[idx];
    for (int idx = threadIdx.x; idx < K2 * 128; idx += 512) wl[K1 * 128 + idx] = W2v[idx];
    for (int idx = threadIdx.x; idx < K2 * 128; idx += 512) wl[(K1 + K2) * 128 + idx] = W2vg[idx];
    __syncthreads();

    const int esub = threadIdx.x >> 7;            // wave-uniform (2 waves per slot)
    const int base = blockIdx.x * 64 + esub * 4;

    #pragma unroll 1
    for (int it = 0; it < 4; ++it) {
        const int j0 = base + it * 16;

        int e[4], s[4], t[4];
        float dd[4];
        #pragma unroll
        for (int u = 0; u < 4; ++u) {
            e[u] = __builtin_amdgcn_readfirstlane(eperm[j0 + u]);
            s[u] = __builtin_amdgcn_readfirstlane(esrc[e[u]]);
            t[u] = __builtin_amdgcn_readfirstlane(etgt[e[u]]);
            dd[u] = dist[e[u]];
        }

        // issue all 32 P-gathers up front (long-latency, independent);
        // sorted order makes the s[u]-side rows L1/L2-resident
        float g0[4], g1[4], g2t[4], g2s[4], m0[4], m1[4], m2t[4], m2s[4];
        #pragma unroll
        for (int u = 0; u < 4; ++u) {
            const float* Ps = P + (size_t)s[u] * 768;
            const float* Pt = P + (size_t)t[u] * 768;
            g0[u]  = Ps[f];
            g2s[u] = Ps[256 + f];
            m0[u]  = Ps[384 + f];
            m2s[u] = Ps[640 + f];
            g1[u]  = Pt[128 + f];
            g2t[u] = Pt[256 + f];
            m1[u]  = Pt[512 + f];
            m2t[u] = Pt[640 + f];
        }

        // edge-feature dot products, k outermost: each LDS weight read is
        // amortized over 4 edges; cs/pw rows are wave-uniform -> scalar loads
        float z1[4] = {}, za[4] = {}, zb[4] = {};
        #pragma unroll
        for (int k = 0; k < K1; ++k) {
            const float wv = wl[k * 128 + f];
            #pragma unroll
            for (int u = 0; u < 4; ++u)
                z1[u] = fmaf(cs[(size_t)e[u] * K1 + k], wv, z1[u]);
        }
        #pragma unroll
        for (int k = 0; k < K2; ++k) {
            const float wa = wl[(K1 + k) * 128 + f];
            const float wb = wl[(K1 + K2 + k) * 128 + f];
            #pragma unroll
            for (int u = 0; u < 4; ++u) {
                const float p = pw[(size_t)e[u] * K2 + k];
                za[u] = fmaf(p, wa, za[u]);
                zb[u] = fmaf(p, wb, zb[u]);
            }
        }

        float z[4];
        #pragma unroll
        for (int u = 0; u < 4; ++u) {
            const float invd = __builtin_amdgcn_rcpf(dd[u]);
            const float g = g0[u] + g1[u] + (g2t[u] - g2s[u]) * invd;
            const float m = m0[u] + m1[u] + (m2t[u] - m2s[u]) * invd;
            z[u] = fsig(g) * felu(m) * (z1[u] + za[u] * fsig(zb[u]));
        }

        // merge same-source runs (common in sorted order) -> fewer atomics
        float acc = z[0];
        #pragma unroll
        for (int u = 1; u < 4; ++u) {
            if (s[u] == s[u - 1]) {
                acc += z[u];
            } else {
                atomicAdd(x + (size_t)s[u - 1] * 128 + f, acc);
                acc = z[u];
            }
        }
        atomicAdd(x + (size_t)s[3] * 128 + f, acc);
    }
}

// ---------------------------------------------------------------------------
// Pool + psi elementwise: T[n][3][128] = [x@Wp1, x@Wp2, x@Wpsi]
// pools[g] += elu(T0)*T1 ; xout = elu(T2)
// ---------------------------------------------------------------------------
__global__ __launch_bounds__(256) void pool_psi_kernel(
    const float* __restrict__ T, const int* __restrict__ gidx,
    float* __restrict__ pools, float* __restrict__ xout)
{
    int idx = blockIdx.x * 256 + threadIdx.x;
    int n = idx >> 7, f = idx & 127;
    float h1 = eluf(T[(size_t)n * 384 + f]);
    float h2 = T[(size_t)n * 384 + 128 + f];
    atomicAdd(pools + (size_t)gidx[n] * 128 + f, h1 * h2);
    xout[(size_t)n * 128 + f] = eluf(T[(size_t)n * 384 + 256 + f]);
}

// ---------------------------------------------------------------------------
// Final head: per graph: elu(@Wlr1[128,64]) -> elu(@Wlr2[64,42]) -> @Wlr3[42,1]
// ---------------------------------------------------------------------------
__global__ __launch_bounds__(64) void final_kernel(
    const float* __restrict__ pools,
    const float* __restrict__ Wlr1, const float* __restrict__ Wlr2,
    const float* __restrict__ Wlr3, float* __restrict__ out)
{
    __shared__ float h1[64];
    __shared__ float h2[42];
    const int g = blockIdx.x;
    const int f = threadIdx.x;

    float a = 0.f;
    #pragma unroll 8
    for (int k = 0; k < 128; ++k) a = fmaf(pools[(size_t)g * 128 + k], Wlr1[k * 64 + f], a);
    h1[f] = eluf(a);
    __syncthreads();
    if (f < 42) {
        float b = 0.f;
        #pragma unroll
        for (int k = 0; k < 64; ++k) b = fmaf(h1[k], Wlr2[k * 42 + f], b);
        h2[f] = eluf(b);
    }
    __syncthreads();
    if (f == 0) {
        float c = 0.f;
        #pragma unroll
        for (int k = 0; k < 42; ++k) c = fmaf(h2[k], Wlr3[k], c);
        out[g] = c;
    }
}

__global__ void zero_kernel(float* p, int n)
{
    int i = blockIdx.x * 256 + threadIdx.x;
    if (i < n) p[i] = 0.f;
}

extern "C" void kernel_launch(void* const* d_in, const int* in_sizes, int n_in,
                              void* d_out, int out_size, void* d_ws, size_t ws_size,
                              hipStream_t stream)
{
    const float* nodes = (const float*)d_in[0];
    const int*   esrc  = (const int*)d_in[1];
    const int*   etgt  = (const int*)d_in[2];
    const float* dist  = (const float*)d_in[3];
    const int*   gidx  = (const int*)d_in[4];
    // d_in[5] = node_counts : unused (division discarded in the source)
    const float* cs    = (const float*)d_in[6];
    const float* pw    = (const float*)d_in[7];
    const float* W_emb = (const float*)d_in[8];
    const float* Wg    = (const float*)d_in[9];
    const float* Wm    = (const float*)d_in[10];
    const float* W1v   = (const float*)d_in[11];
    const float* W2v   = (const float*)d_in[12];
    const float* W2vg  = (const float*)d_in[13];
    const float* Wp1   = (const float*)d_in[14];
    const float* Wp2   = (const float*)d_in[15];
    const float* Wpsi  = (const float*)d_in[16];
    const float* Wlr1  = (const float*)d_in[17];
    const float* Wlr2  = (const float*)d_in[18];
    const float* Wlr3  = (const float*)d_in[19];
    float* outp = (float*)d_out;

    // workspace layout (floats): xA | xB | P(=T overlay) | pools | sort scratch
    float* xA    = (float*)d_ws;
    float* xB    = xA + (size_t)NNODES * 128;
    float* P     = xB + (size_t)NNODES * 128;
    float* pools = P + (size_t)NNODES * 768;     // ~82 MB so far
    int* cnt     = (int*)(pools + NGRAPHS * 128);
    int* cursor  = cnt + NBINS;
    int* eperm   = cursor + NBINS;               // +1.4 MB

    zero_kernel<<<100, 256, 0, stream>>>(pools, NGRAPHS * 128);

    // build source-sorted edge permutation (sources invariant across blocks)
    zero_kernel<<<(NBINS + 255) / 256, 256, 0, stream>>>((float*)cnt, NBINS);
    hist_kernel<<<(NEDGES + 255) / 256, 256, 0, stream>>>(esrc, cnt);
    scan_kernel<<<1, 1024, 0, stream>>>(cnt, cursor);
    scatter_kernel<<<(NEDGES + 255) / 256, 256, 0, stream>>>(esrc, cursor, eperm);

    // x = sigmoid(nodes @ W_emb)
    {
        WPtrs wp{}; wp.w[0] = W_emb;
        gemm128_kernel<<<dim3(313, 2), 256, 0, stream>>>(nodes, wp, xA, 128, 1);
    }

    float* xc = xA;
    float* xn = xB;
    for (int i = 0; i < 3; ++i) {
        // P = x @ [Wg0,Wg1,Wg2,Wm0,Wm1,Wm2]  (each 128x128, contiguous in Wg/Wm)
        WPtrs wp{};
        const float* Wgi = Wg + (size_t)i * 49152;
        const float* Wmi = Wm + (size_t)i * 49152;
        wp.w[0] = Wgi;          wp.w[1] = Wgi + 16384;  wp.w[2] = Wgi + 32768;
        wp.w[3] = Wmi;          wp.w[4] = Wmi + 16384;  wp.w[5] = Wmi + 32768;
        gemm128_kernel<<<dim3(313, 12), 256, 0, stream>>>(xc, wp, P, 768, 0);

        // gather/combine/scatter over edges in source-sorted order
        edge_kernel<<<5000, 512, 0, stream>>>(P, eperm, esrc, etgt, dist, cs, pw,
            W1v + (size_t)i * (K1 * 128),
            W2v + (size_t)i * (K2 * 128),
            W2vg + (size_t)i * (K2 * 128), xc);

        // T = x @ [Wp1, Wp2, Wpsi]  (reuse P buffer)
        WPtrs wq{};
        wq.w[0] = Wp1 + (size_t)i * 16384;
        wq.w[1] = Wp2 + (size_t)i * 16384;
        wq.w[2] = Wpsi + (size_t)i * 16384;
        gemm128_kernel<<<dim3(313, 6), 256, 0, stream>>>(xc, wq, P, 384, 0);

        // pools[g] += elu(T0)*T1 ; xn = elu(T2)
        pool_psi_kernel<<<10000, 256, 0, stream>>>(P, gidx, pools, xn);

        float* tmp = xc; xc = xn; xn = tmp;
    }

    final_kernel<<<NGRAPHS, 64, 0, stream>>>(pools, Wlr1, Wlr2, Wlr3, outp);
}